// Round 1
// baseline (752.705 us; speedup 1.0000x reference)
//
#include <hip/hip_runtime.h>
#include <math.h>

#define Bn 512

// ws layout (4-byte words):
// [0]        float acc        (global sum of all fiber terms)
// [1]        int   n_plus
// [16..528)  int   cls[512]

__global__ void prep_kernel(const float* __restrict__ target,
                            int* __restrict__ cls,
                            int* __restrict__ nplus,
                            float* __restrict__ acc) {
    __shared__ int cnt;
    const int t = threadIdx.x;
    if (t == 0) cnt = 0;
    __syncthreads();
    // class: round-half-even(target) >= 0  (jnp.round == rintf)
    const int c = (rintf(target[t]) >= 0.0f) ? 1 : 0;
    cls[t] = c;
    atomicAdd(&cnt, c);
    __syncthreads();
    if (t == 0) { *nplus = cnt; *acc = 0.0f; }
}

__global__ __launch_bounds__(256) void conloss_main(
    const float* __restrict__ cube,
    const int* __restrict__ cls,
    const int* __restrict__ nplus_p,
    float* __restrict__ acc)
{
    __shared__ int   sc[Bn];
    __shared__ float sE[4][Bn];   // per-wave column partials (exp-sums)
    __shared__ float sS[4][Bn];   // per-wave column partials (masked x-sums)
    __shared__ float sred[256];

    const int tid = threadIdx.x;
    for (int t = tid; t < Bn; t += 256) sc[t] = cls[t];
    __syncthreads();
    const int np = *nplus_p;
    const int bid = blockIdx.x;
    float total = 0.0f;

    if (bid < Bn) {
        // ---- Pass A: slice i = bid. Covers axis=2 (rows, over k) and axis=1
        // (columns, over j) fibers; both have fixed-index i => class g = c_i.
        const int i = bid;
        const int ci = sc[i];
        const float inv_ng = 1.0f / (float)(ci ? np : (Bn - np));
        const int wave = tid >> 6;
        const int lane = tid & 63;
        const float* slice = cube + (size_t)i * (size_t)(Bn * Bn);
        const int ka = 4 * lane;        // owns k = ka..ka+3
        const int kb = 256 + 4 * lane;  // and  k = kb..kb+3

        float4 km_a, km_b;  // 1.0 where sc[k]==ci (mask over k, row-invariant)
        km_a.x = (sc[ka+0] == ci) ? 1.0f : 0.0f;
        km_a.y = (sc[ka+1] == ci) ? 1.0f : 0.0f;
        km_a.z = (sc[ka+2] == ci) ? 1.0f : 0.0f;
        km_a.w = (sc[ka+3] == ci) ? 1.0f : 0.0f;
        km_b.x = (sc[kb+0] == ci) ? 1.0f : 0.0f;
        km_b.y = (sc[kb+1] == ci) ? 1.0f : 0.0f;
        km_b.z = (sc[kb+2] == ci) ? 1.0f : 0.0f;
        km_b.w = (sc[kb+3] == ci) ? 1.0f : 0.0f;

        float4 cE_a = make_float4(0.f,0.f,0.f,0.f), cE_b = make_float4(0.f,0.f,0.f,0.f);
        float4 cS_a = make_float4(0.f,0.f,0.f,0.f), cS_b = make_float4(0.f,0.f,0.f,0.f);

        for (int j = wave; j < Bn; j += 4) {
            const float* row = slice + (size_t)j * Bn;
            const float4 xa = *(const float4*)(row + ka);
            const float4 xb = *(const float4*)(row + kb);
            float4 ea, eb;
            ea.x = __expf(xa.x); ea.y = __expf(xa.y); ea.z = __expf(xa.z); ea.w = __expf(xa.w);
            eb.x = __expf(xb.x); eb.y = __expf(xb.y); eb.z = __expf(xb.z); eb.w = __expf(xb.w);

            // column (axis=1) accumulators: over j, mask on c_j
            const float jm = (sc[j] == ci) ? 1.0f : 0.0f;
            cE_a.x += ea.x; cE_a.y += ea.y; cE_a.z += ea.z; cE_a.w += ea.w;
            cE_b.x += eb.x; cE_b.y += eb.y; cE_b.z += eb.z; cE_b.w += eb.w;
            cS_a.x += jm * xa.x; cS_a.y += jm * xa.y; cS_a.z += jm * xa.z; cS_a.w += jm * xa.w;
            cS_b.x += jm * xb.x; cS_b.y += jm * xb.y; cS_b.z += jm * xb.z; cS_b.w += jm * xb.w;

            // row (axis=2) reduction over k, mask on c_k
            float rE = ((ea.x + ea.y) + (ea.z + ea.w)) + ((eb.x + eb.y) + (eb.z + eb.w));
            float rS = km_a.x * xa.x + km_a.y * xa.y + km_a.z * xa.z + km_a.w * xa.w
                     + km_b.x * xb.x + km_b.y * xb.y + km_b.z * xb.z + km_b.w * xb.w;
            #pragma unroll
            for (int off = 32; off > 0; off >>= 1) {
                rE += __shfl_xor(rE, off, 64);
                rS += __shfl_xor(rS, off, 64);
            }
            if (lane == 0) {
                total += jm * (__logf(rE) - rS * inv_ng);
            }
        }

        // combine the 4 waves' column partials via LDS
        sE[wave][ka+0] = cE_a.x; sE[wave][ka+1] = cE_a.y; sE[wave][ka+2] = cE_a.z; sE[wave][ka+3] = cE_a.w;
        sE[wave][kb+0] = cE_b.x; sE[wave][kb+1] = cE_b.y; sE[wave][kb+2] = cE_b.z; sE[wave][kb+3] = cE_b.w;
        sS[wave][ka+0] = cS_a.x; sS[wave][ka+1] = cS_a.y; sS[wave][ka+2] = cS_a.z; sS[wave][ka+3] = cS_a.w;
        sS[wave][kb+0] = cS_b.x; sS[wave][kb+1] = cS_b.y; sS[wave][kb+2] = cS_b.z; sS[wave][kb+3] = cS_b.w;
        __syncthreads();
        for (int k = tid; k < Bn; k += 256) {
            const float ce = (sE[0][k] + sE[1][k]) + (sE[2][k] + sE[3][k]);
            const float cs = (sS[0][k] + sS[1][k]) + (sS[2][k] + sS[3][k]);
            const float m = (sc[k] == ci) ? 1.0f : 0.0f;
            total += m * (__logf(ce) - cs * inv_ng);
        }
    } else {
        // ---- Pass B: plane j = bid-512. Axis=0 fibers (over i), fixed (j,k),
        // class g = c_j (requires c_k == c_j).
        const int j = bid - Bn;
        const int cj = sc[j];
        const float inv_ng = 1.0f / (float)(cj ? np : (Bn - np));
        const float* base = cube + (size_t)j * Bn;
        const int k0 = 2 * tid;
        float2 E = make_float2(0.f, 0.f), S = make_float2(0.f, 0.f);
        #pragma unroll 8
        for (int ii = 0; ii < Bn; ++ii) {
            const float2 x = *(const float2*)(base + (size_t)ii * (size_t)(Bn * Bn) + k0);
            const float im = (sc[ii] == cj) ? 1.0f : 0.0f;
            E.x += __expf(x.x); E.y += __expf(x.y);
            S.x += im * x.x;    S.y += im * x.y;
        }
        const float m0 = (sc[k0]   == cj) ? 1.0f : 0.0f;
        const float m1 = (sc[k0+1] == cj) ? 1.0f : 0.0f;
        total += m0 * (__logf(E.x) - S.x * inv_ng);
        total += m1 * (__logf(E.y) - S.y * inv_ng);
    }

    // block reduction -> one atomic per block
    sred[tid] = total;
    __syncthreads();
    for (int s = 128; s > 0; s >>= 1) {
        if (tid < s) sred[tid] += sred[tid + s];
        __syncthreads();
    }
    if (tid == 0) atomicAdd(acc, sred[0]);
}

__global__ void finalize_kernel(const float* __restrict__ acc, float* __restrict__ out) {
    out[0] = acc[0] * (1.0f / ((float)Bn * (float)Bn));
}

extern "C" void kernel_launch(void* const* d_in, const int* in_sizes, int n_in,
                              void* d_out, int out_size, void* d_ws, size_t ws_size,
                              hipStream_t stream) {
    const float* cube   = (const float*)d_in[0];   // (512,512,512) fp32
    const float* target = (const float*)d_in[1];   // (512,1) fp32
    float* out = (float*)d_out;

    float* acc   = (float*)d_ws;
    int*   nplus = (int*)d_ws + 1;
    int*   cls   = (int*)d_ws + 16;

    prep_kernel<<<1, Bn, 0, stream>>>(target, cls, nplus, acc);
    conloss_main<<<2 * Bn, 256, 0, stream>>>(cube, cls, nplus, acc);
    finalize_kernel<<<1, 1, 0, stream>>>(acc, out);
}

// Round 3
// 730.482 us; speedup vs baseline: 1.0304x; 1.0304x over previous
//
#include <hip/hip_runtime.h>
#include <math.h>

#define Bn 512

typedef float fx4 __attribute__((ext_vector_type(4)));

// ws layout (4-byte words):
// [0]        float acc        (global sum of all fiber terms)
// [1]        int   n_plus
// [16..528)  int   cls[512]

__device__ __forceinline__ float4 ntload4(const float* p) {
    fx4 v = __builtin_nontemporal_load((const fx4*)p);
    return make_float4(v.x, v.y, v.z, v.w);
}

__global__ void prep_kernel(const float* __restrict__ target,
                            int* __restrict__ cls,
                            int* __restrict__ nplus,
                            float* __restrict__ acc) {
    __shared__ int cnt;
    const int t = threadIdx.x;
    if (t == 0) cnt = 0;
    __syncthreads();
    // class: round-half-even(target) >= 0  (jnp.round == rintf)
    const int c = (rintf(target[t]) >= 0.0f) ? 1 : 0;
    cls[t] = c;
    atomicAdd(&cnt, c);
    __syncthreads();
    if (t == 0) { *nplus = cnt; *acc = 0.0f; }
}

__global__ __launch_bounds__(256) void conloss_main(
    const float* __restrict__ cube,
    const int* __restrict__ cls,
    const int* __restrict__ nplus_p,
    float* __restrict__ acc)
{
    __shared__ int   sc[Bn];
    __shared__ float sE[4][Bn];   // pass A: per-wave column partials; pass B: half partials
    __shared__ float sS[4][Bn];
    __shared__ float sred[256];

    const int tid = threadIdx.x;
    for (int t = tid; t < Bn; t += 256) sc[t] = cls[t];
    __syncthreads();
    const int np = *nplus_p;
    const int bid = blockIdx.x;
    float total = 0.0f;

    if ((bid & 1) == 0) {
        // ---- Pass A: slice i. Covers axis=2 (rows, over k) and axis=1
        // (columns, over j) fibers; both have fixed-index i => class g = c_i.
        const int i = bid >> 1;
        const int ci = sc[i];
        const float inv_ng = 1.0f / (float)(ci ? np : (Bn - np));
        const int wave = tid >> 6;
        const int lane = tid & 63;
        const float* slice = cube + (size_t)i * (size_t)(Bn * Bn);
        const int ka = 4 * lane;        // owns k = ka..ka+3
        const int kb = 256 + 4 * lane;  // and  k = kb..kb+3

        float4 km_a, km_b;  // 1.0 where sc[k]==ci (mask over k, row-invariant)
        km_a.x = (sc[ka+0] == ci) ? 1.0f : 0.0f;
        km_a.y = (sc[ka+1] == ci) ? 1.0f : 0.0f;
        km_a.z = (sc[ka+2] == ci) ? 1.0f : 0.0f;
        km_a.w = (sc[ka+3] == ci) ? 1.0f : 0.0f;
        km_b.x = (sc[kb+0] == ci) ? 1.0f : 0.0f;
        km_b.y = (sc[kb+1] == ci) ? 1.0f : 0.0f;
        km_b.z = (sc[kb+2] == ci) ? 1.0f : 0.0f;
        km_b.w = (sc[kb+3] == ci) ? 1.0f : 0.0f;

        float4 cE_a = make_float4(0.f,0.f,0.f,0.f), cE_b = make_float4(0.f,0.f,0.f,0.f);
        float4 cS_a = make_float4(0.f,0.f,0.f,0.f), cS_b = make_float4(0.f,0.f,0.f,0.f);

        for (int j = wave; j < Bn; j += 4) {
            const float* row = slice + (size_t)j * Bn;
            const float4 xa = ntload4(row + ka);
            const float4 xb = ntload4(row + kb);
            float4 ea, eb;
            ea.x = __expf(xa.x); ea.y = __expf(xa.y); ea.z = __expf(xa.z); ea.w = __expf(xa.w);
            eb.x = __expf(xb.x); eb.y = __expf(xb.y); eb.z = __expf(xb.z); eb.w = __expf(xb.w);

            // column (axis=1) accumulators: over j, mask on c_j
            const float jm = (sc[j] == ci) ? 1.0f : 0.0f;
            cE_a.x += ea.x; cE_a.y += ea.y; cE_a.z += ea.z; cE_a.w += ea.w;
            cE_b.x += eb.x; cE_b.y += eb.y; cE_b.z += eb.z; cE_b.w += eb.w;
            cS_a.x += jm * xa.x; cS_a.y += jm * xa.y; cS_a.z += jm * xa.z; cS_a.w += jm * xa.w;
            cS_b.x += jm * xb.x; cS_b.y += jm * xb.y; cS_b.z += jm * xb.z; cS_b.w += jm * xb.w;

            // row (axis=2) reduction over k, mask on c_k
            float rE = ((ea.x + ea.y) + (ea.z + ea.w)) + ((eb.x + eb.y) + (eb.z + eb.w));
            float rS = km_a.x * xa.x + km_a.y * xa.y + km_a.z * xa.z + km_a.w * xa.w
                     + km_b.x * xb.x + km_b.y * xb.y + km_b.z * xb.z + km_b.w * xb.w;
            #pragma unroll
            for (int off = 32; off > 0; off >>= 1) {
                rE += __shfl_xor(rE, off, 64);
                rS += __shfl_xor(rS, off, 64);
            }
            if (lane == 0) {
                total += jm * (__logf(rE) - rS * inv_ng);
            }
        }

        // combine the 4 waves' column partials via LDS
        sE[wave][ka+0] = cE_a.x; sE[wave][ka+1] = cE_a.y; sE[wave][ka+2] = cE_a.z; sE[wave][ka+3] = cE_a.w;
        sE[wave][kb+0] = cE_b.x; sE[wave][kb+1] = cE_b.y; sE[wave][kb+2] = cE_b.z; sE[wave][kb+3] = cE_b.w;
        sS[wave][ka+0] = cS_a.x; sS[wave][ka+1] = cS_a.y; sS[wave][ka+2] = cS_a.z; sS[wave][ka+3] = cS_a.w;
        sS[wave][kb+0] = cS_b.x; sS[wave][kb+1] = cS_b.y; sS[wave][kb+2] = cS_b.z; sS[wave][kb+3] = cS_b.w;
        __syncthreads();
        for (int k = tid; k < Bn; k += 256) {
            const float ce = (sE[0][k] + sE[1][k]) + (sE[2][k] + sE[3][k]);
            const float cs = (sS[0][k] + sS[1][k]) + (sS[2][k] + sS[3][k]);
            const float m = (sc[k] == ci) ? 1.0f : 0.0f;
            total += m * (__logf(ce) - cs * inv_ng);
        }
    } else {
        // ---- Pass B: plane j. Axis=0 fibers (over i), fixed (j,k),
        // class g = c_j (requires c_k == c_j).
        // 2 slices in flight per iteration: threads [0,128) take even slice,
        // [128,256) odd slice; each thread owns 4 consecutive k (float4 load).
        const int j = bid >> 1;
        const int cj = sc[j];
        const float inv_ng = 1.0f / (float)(cj ? np : (Bn - np));
        const float* base = cube + (size_t)j * Bn;
        const int half = tid >> 7;       // which slice parity this thread covers
        const int t    = tid & 127;
        const int k0 = 4 * t;
        float4 E = make_float4(0.f,0.f,0.f,0.f);
        float4 S = make_float4(0.f,0.f,0.f,0.f);
        #pragma unroll 8
        for (int ii = 0; ii < Bn / 2; ++ii) {
            const int s = 2 * ii + half;
            const float4 x = ntload4(base + (size_t)s * (size_t)(Bn * Bn) + k0);
            const float im = (sc[s] == cj) ? 1.0f : 0.0f;
            E.x += __expf(x.x); E.y += __expf(x.y); E.z += __expf(x.z); E.w += __expf(x.w);
            S.x += im * x.x;    S.y += im * x.y;    S.z += im * x.z;    S.w += im * x.w;
        }
        // combine even/odd halves via LDS
        sE[half][k0+0] = E.x; sE[half][k0+1] = E.y; sE[half][k0+2] = E.z; sE[half][k0+3] = E.w;
        sS[half][k0+0] = S.x; sS[half][k0+1] = S.y; sS[half][k0+2] = S.z; sS[half][k0+3] = S.w;
        __syncthreads();
        if (half == 0) {
            #pragma unroll
            for (int q = 0; q < 4; ++q) {
                const int k = k0 + q;
                const float e = sE[0][k] + sE[1][k];
                const float s = sS[0][k] + sS[1][k];
                const float m = (sc[k] == cj) ? 1.0f : 0.0f;
                total += m * (__logf(e) - s * inv_ng);
            }
        }
    }

    // block reduction -> one atomic per block
    sred[tid] = total;
    __syncthreads();
    for (int s = 128; s > 0; s >>= 1) {
        if (tid < s) sred[tid] += sred[tid + s];
        __syncthreads();
    }
    if (tid == 0) atomicAdd(acc, sred[0]);
}

__global__ void finalize_kernel(const float* __restrict__ acc, float* __restrict__ out) {
    out[0] = acc[0] * (1.0f / ((float)Bn * (float)Bn));
}

extern "C" void kernel_launch(void* const* d_in, const int* in_sizes, int n_in,
                              void* d_out, int out_size, void* d_ws, size_t ws_size,
                              hipStream_t stream) {
    const float* cube   = (const float*)d_in[0];   // (512,512,512) fp32
    const float* target = (const float*)d_in[1];   // (512,1) fp32
    float* out = (float*)d_out;

    float* acc   = (float*)d_ws;
    int*   nplus = (int*)d_ws + 1;
    int*   cls   = (int*)d_ws + 16;

    prep_kernel<<<1, Bn, 0, stream>>>(target, cls, nplus, acc);
    conloss_main<<<2 * Bn, 256, 0, stream>>>(cube, cls, nplus, acc);
    finalize_kernel<<<1, 1, 0, stream>>>(acc, out);
}